// Round 9
// baseline (143.530 us; speedup 1.0000x reference)
//
#include <hip/hip_runtime.h>
#include <hip/hip_bf16.h>

// Problem dims (AdditiveAttention_56865366999388)
#define NB 4
#define NQL 512   // query length
#define ML 512    // key/value length
#define DDIM 256  // DQ == DK == DV
#define HDIM 256  // H

static constexpr float TWO_LOG2E = 2.8853900817779268f; // 2*log2(e)
static constexpr float LOG2E     = 1.4426950408889634f;

// ---------------------------------------------------------------------------
// Kernel 1: projection + exp.  (byte-identical to the 133.6us r8 kernel)
// ---------------------------------------------------------------------------
__global__ __launch_bounds__(256) void proj_kernel(
    const float* __restrict__ q_src, const float* __restrict__ k_src,
    const float* __restrict__ Wq,    const float* __restrict__ Wk,
    float* __restrict__ EqT,         float* __restrict__ EkT)
{
    const int z = blockIdx.z;
    const int b = z & 3;
    const int which = z >> 2;
    const float* __restrict__ src  = which ? k_src : q_src;
    const float* __restrict__ W    = which ? Wk    : Wq;
    float* __restrict__       outT = which ? EkT   : EqT;

    const int l0 = blockIdx.x * 32;
    const int h0 = blockIdx.y * 64;
    const int t  = threadIdx.x;
    const int tx = t & 15;   // h group (4 each)
    const int ty = t >> 4;   // l (2 each)

    __shared__ float sX[32][36];   // [dd][ll]  32d x 32l
    __shared__ float sW[32][68];   // [dd][hh]  32d x 64h

    float acc[2][4];
    #pragma unroll
    for (int i = 0; i < 2; i++)
        #pragma unroll
        for (int j = 0; j < 4; j++) acc[i][j] = 0.f;

    const int llA = t >> 3, dgA = t & 7;   // X: 32 l rows x 8 d-groups(4)
    const int ddB = t >> 3, hgB = t & 7;   // W: 32 d rows x 8 h-groups(8)

    for (int d0 = 0; d0 < DDIM; d0 += 32) {
        float4 xv = *(const float4*)&src[(size_t)(b * NQL + l0 + llA) * DDIM + d0 + dgA * 4];
        const float* wrow = &W[(size_t)(d0 + ddB) * HDIM + h0 + hgB * 8];
        float4 wa = ((const float4*)wrow)[0];
        float4 wb = ((const float4*)wrow)[1];
        __syncthreads();
        sX[dgA * 4 + 0][llA] = xv.x;
        sX[dgA * 4 + 1][llA] = xv.y;
        sX[dgA * 4 + 2][llA] = xv.z;
        sX[dgA * 4 + 3][llA] = xv.w;
        *(float4*)&sW[ddB][hgB * 8]     = wa;
        *(float4*)&sW[ddB][hgB * 8 + 4] = wb;
        __syncthreads();
        #pragma unroll
        for (int dd = 0; dd < 32; dd++) {
            float4 w4 = *(const float4*)&sW[dd][tx * 4];
            float2 x2 = *(const float2*)&sX[dd][ty * 2];
            acc[0][0] = fmaf(x2.x, w4.x, acc[0][0]);
            acc[0][1] = fmaf(x2.x, w4.y, acc[0][1]);
            acc[0][2] = fmaf(x2.x, w4.z, acc[0][2]);
            acc[0][3] = fmaf(x2.x, w4.w, acc[0][3]);
            acc[1][0] = fmaf(x2.y, w4.x, acc[1][0]);
            acc[1][1] = fmaf(x2.y, w4.y, acc[1][1]);
            acc[1][2] = fmaf(x2.y, w4.z, acc[1][2]);
            acc[1][3] = fmaf(x2.y, w4.w, acc[1][3]);
        }
    }

    #pragma unroll
    for (int j = 0; j < 4; j++) {
        float2 o;
        o.x = __builtin_amdgcn_exp2f(acc[0][j] * TWO_LOG2E);
        o.y = __builtin_amdgcn_exp2f(acc[1][j] * TWO_LOG2E);
        *(float2*)&outT[(size_t)(b * HDIM + h0 + tx * 4 + j) * NQL + l0 + ty * 2] = o;
    }
}

// ---------------------------------------------------------------------------
// Kernel 2: scores + exp + partial row sums.  (byte-identical to r8)
// ---------------------------------------------------------------------------
__global__ __launch_bounds__(256) void scores_kernel(
    const float* __restrict__ EqT, const float* __restrict__ EkT,
    const float* __restrict__ Wv, float* __restrict__ P,
    float* __restrict__ Spart)
{
    const int b  = blockIdx.z;
    const int mt = blockIdx.x;
    const int m0 = mt * 32;
    const int n0 = blockIdx.y * 32;
    const int t  = threadIdx.x;
    const int tx = t & 15;   // m (2 each)
    const int ty = t >> 4;   // n (2 each)

    __shared__ float sQ[32][36];   // [hh][nn]
    __shared__ float sK[32][36];   // [hh][mm]
    __shared__ float sWV[32];

    float acc00 = 0.f, acc01 = 0.f, acc10 = 0.f, acc11 = 0.f;
    float swv = 0.f;

    const int hhA = t >> 3, cgA = t & 7;  // staging: 32 h rows x 8 col-groups(4)

    for (int h0 = 0; h0 < HDIM; h0 += 32) {
        float4 qv = *(const float4*)&EqT[(size_t)(b * HDIM + h0 + hhA) * NQL + n0 + cgA * 4];
        float4 kv = *(const float4*)&EkT[(size_t)(b * HDIM + h0 + hhA) * ML  + m0 + cgA * 4];
        float wv_ld = (t < 32) ? Wv[h0 + t] : 0.f;
        __syncthreads();
        *(float4*)&sQ[hhA][cgA * 4] = qv;
        *(float4*)&sK[hhA][cgA * 4] = kv;
        if (t < 32) sWV[t] = wv_ld;
        __syncthreads();
        #pragma unroll 8
        for (int hh = 0; hh < 32; hh++) {
            float2 q2 = *(const float2*)&sQ[hh][ty * 2];
            float2 k2 = *(const float2*)&sK[hh][tx * 2];
            float wv = sWV[hh];
            swv += wv;
            const float nw2 = -2.0f * wv;
            float a00 = fmaf(q2.x, k2.x, 1.0f);   // e^{2(q+k)} + 1
            float a01 = fmaf(q2.x, k2.y, 1.0f);
            float a10 = fmaf(q2.y, k2.x, 1.0f);
            float a11 = fmaf(q2.y, k2.y, 1.0f);
            float r0 = __builtin_amdgcn_rcpf(a00 * a01);
            float r1 = __builtin_amdgcn_rcpf(a10 * a11);
            acc00 = fmaf(nw2, r0 * a01, acc00);
            acc01 = fmaf(nw2, r0 * a00, acc01);
            acc10 = fmaf(nw2, r1 * a11, acc10);
            acc11 = fmaf(nw2, r1 * a10, acc11);
        }
    }

    // epilogue: P = exp(S) + per-block partial rowsums
    float2 o0, o1;
    o0.x = __builtin_amdgcn_exp2f((swv + acc00) * LOG2E);
    o0.y = __builtin_amdgcn_exp2f((swv + acc01) * LOG2E);
    o1.x = __builtin_amdgcn_exp2f((swv + acc10) * LOG2E);
    o1.y = __builtin_amdgcn_exp2f((swv + acc11) * LOG2E);
    *(float2*)&P[(size_t)(b * NQL + n0 + ty * 2 + 0) * ML + m0 + tx * 2] = o0;
    *(float2*)&P[(size_t)(b * NQL + n0 + ty * 2 + 1) * ML + m0 + tx * 2] = o1;

    float rs0 = o0.x + o0.y;
    float rs1 = o1.x + o1.y;
    #pragma unroll
    for (int off = 1; off < 16; off <<= 1) {
        rs0 += __shfl_xor(rs0, off);
        rs1 += __shfl_xor(rs1, off);
    }
    if (tx == 0) {
        Spart[(size_t)(mt * NB + b) * NQL + n0 + ty * 2 + 0] = rs0;
        Spart[(size_t)(mt * NB + b) * NQL + n0 + ty * 2 + 1] = rs1;
    }
}

// ---------------------------------------------------------------------------
// Kernel 3 (THE ONE CHANGE): out[b][n][v] = (sum_m P * V) / rowsum.
// Retiled 1n x 4v -> 4n x 4v per thread (r6-scores lesson: LDS cy/eval
// 0.070 -> 0.0234, 16 fma per {a b128 + v b128}). m split 4-ways across
// the block's waves (wave w: m in [128w, 128w+128)), 4->1 LDS epilogue
// reduce + fused 1/rowsum. 16n x 64v tile, 256 thr, grid (4,32,4) = 512
// blocks = 2/CU. Same 2-barrier-per-chunk sync structure as r0/r8.
// ---------------------------------------------------------------------------
__global__ __launch_bounds__(256) void av_kernel(
    const float* __restrict__ A, const float* __restrict__ Spart,
    const float* __restrict__ V, float* __restrict__ O)
{
    const int b  = blockIdx.z;
    const int v0 = blockIdx.x * 64;
    const int n0 = blockIdx.y * 16;
    const int t  = threadIdx.x;
    const int lane = t & 63;
    const int w    = t >> 6;     // m-quarter selector (4 waves)
    const int tx   = lane & 15;  // v quad (4 each)
    const int tn   = lane >> 4;  // n quad (4 rows each)

    __shared__ float sA[4][32][20];     // [w][mm][nn] 10.2 KB
    __shared__ float sV[4][32][68];     // [w][mm][vv] 34.8 KB
    __shared__ float sRed[3][16][64];   // 12 KB epilogue reduce
    __shared__ float sInv[16];

    if (t < 16) {   // softmax denominators from the 16 scores partials
        float s = 0.f;
        #pragma unroll
        for (int mt = 0; mt < 16; ++mt)
            s += Spart[(size_t)(mt * NB + b) * NQL + n0 + t];
        sInv[t] = 1.0f / s;
    }

    // staging decompositions (all 256 threads cooperate):
    // A: 16 nn x 4 wg x 4 mg -> 8 floats (2xf4 along m), transposed into sA
    const int nnA = t & 15, wgA = (t >> 4) & 3, mgA = t >> 6;
    // V: 4 vw x 32 mrows x 2 vg -> 32 floats (8xf4 along v), direct copy
    const int vwV = t >> 6, mrV = (t >> 1) & 31, vgV = t & 1;

    const float* abase = &A[(size_t)(b * NQL + n0 + nnA) * ML + wgA * 128 + mgA * 8];
    const float* vbase = &V[(size_t)(b * ML + vwV * 128 + mrV) * DDIM + v0 + vgV * 32];

    float acc[4][4] = {};

    // preload chunk 0
    float4 pa0 = ((const float4*)abase)[0];
    float4 pa1 = ((const float4*)abase)[1];
    float4 pv[8];
    #pragma unroll
    for (int k = 0; k < 8; ++k) pv[k] = ((const float4*)vbase)[k];

    for (int c = 0; c < 4; ++c) {   // 4 chunks of 32 m per wave
        __syncthreads();
        // A transpose-store: sA[wg][m][nn]
        sA[wgA][mgA * 8 + 0][nnA] = pa0.x;
        sA[wgA][mgA * 8 + 1][nnA] = pa0.y;
        sA[wgA][mgA * 8 + 2][nnA] = pa0.z;
        sA[wgA][mgA * 8 + 3][nnA] = pa0.w;
        sA[wgA][mgA * 8 + 4][nnA] = pa1.x;
        sA[wgA][mgA * 8 + 5][nnA] = pa1.y;
        sA[wgA][mgA * 8 + 6][nnA] = pa1.z;
        sA[wgA][mgA * 8 + 7][nnA] = pa1.w;
        #pragma unroll
        for (int k = 0; k < 8; ++k)
            *(float4*)&sV[vwV][mrV][vgV * 32 + k * 4] = pv[k];
        __syncthreads();
        if (c < 3) {    // prefetch next chunk; latency hides under compute
            const float* ap = abase + (c + 1) * 32;
            pa0 = ((const float4*)ap)[0];
            pa1 = ((const float4*)ap)[1];
            const float* vp = vbase + (size_t)(c + 1) * 32 * DDIM;
            #pragma unroll
            for (int k = 0; k < 8; ++k) pv[k] = ((const float4*)vp)[k];
        }
        #pragma unroll
        for (int mm = 0; mm < 32; ++mm) {
            float4 a4 = *(const float4*)&sA[w][mm][tn * 4];   // 4 n (broadcast x16)
            float4 v4 = *(const float4*)&sV[w][mm][tx * 4];   // 4 v
            acc[0][0] = fmaf(a4.x, v4.x, acc[0][0]);
            acc[0][1] = fmaf(a4.x, v4.y, acc[0][1]);
            acc[0][2] = fmaf(a4.x, v4.z, acc[0][2]);
            acc[0][3] = fmaf(a4.x, v4.w, acc[0][3]);
            acc[1][0] = fmaf(a4.y, v4.x, acc[1][0]);
            acc[1][1] = fmaf(a4.y, v4.y, acc[1][1]);
            acc[1][2] = fmaf(a4.y, v4.z, acc[1][2]);
            acc[1][3] = fmaf(a4.y, v4.w, acc[1][3]);
            acc[2][0] = fmaf(a4.z, v4.x, acc[2][0]);
            acc[2][1] = fmaf(a4.z, v4.y, acc[2][1]);
            acc[2][2] = fmaf(a4.z, v4.z, acc[2][2]);
            acc[2][3] = fmaf(a4.z, v4.w, acc[2][3]);
            acc[3][0] = fmaf(a4.w, v4.x, acc[3][0]);
            acc[3][1] = fmaf(a4.w, v4.y, acc[3][1]);
            acc[3][2] = fmaf(a4.w, v4.z, acc[3][2]);
            acc[3][3] = fmaf(a4.w, v4.w, acc[3][3]);
        }
    }

    // 4 -> 1 m-quarter reduce + fused normalization
    if (w != 0) {
        #pragma unroll
        for (int i = 0; i < 4; ++i) {
            float4 r = {acc[i][0], acc[i][1], acc[i][2], acc[i][3]};
            *(float4*)&sRed[w - 1][tn * 4 + i][tx * 4] = r;
        }
    }
    __syncthreads();
    if (w == 0) {
        #pragma unroll
        for (int i = 0; i < 4; ++i) {
            float4 r1 = *(const float4*)&sRed[0][tn * 4 + i][tx * 4];
            float4 r2 = *(const float4*)&sRed[1][tn * 4 + i][tx * 4];
            float4 r3 = *(const float4*)&sRed[2][tn * 4 + i][tx * 4];
            const float inv = sInv[tn * 4 + i];
            float4 o;
            o.x = (acc[i][0] + r1.x + r2.x + r3.x) * inv;
            o.y = (acc[i][1] + r1.y + r2.y + r3.y) * inv;
            o.z = (acc[i][2] + r1.z + r2.z + r3.z) * inv;
            o.w = (acc[i][3] + r1.w + r2.w + r3.w) * inv;
            *(float4*)&O[(size_t)(b * NQL + n0 + tn * 4 + i) * DDIM + v0 + tx * 4] = o;
        }
    }
}

// ---------------------------------------------------------------------------
extern "C" void kernel_launch(void* const* d_in, const int* in_sizes, int n_in,
                              void* d_out, int out_size, void* d_ws, size_t ws_size,
                              hipStream_t stream)
{
    const float* query = (const float*)d_in[0]; // (4,512,256)
    const float* key   = (const float*)d_in[1]; // (4,512,256)
    const float* value = (const float*)d_in[2]; // (4,512,256)
    const float* Wq    = (const float*)d_in[3]; // (256,256)
    const float* Wk    = (const float*)d_in[4]; // (256,256)
    const float* Wv    = (const float*)d_in[5]; // (256,)
    float* out = (float*)d_out;                 // (4,512,256)

    // workspace layout (fp32): EqT 2MB | EkT 2MB | P 4MB | Spart 128KB
    float* EqT   = (float*)d_ws;                      // [4][256][512]
    float* EkT   = EqT + (size_t)NB * HDIM * NQL;     // [4][256][512]
    float* P     = EkT + (size_t)NB * HDIM * ML;      // [4][512][512] (= exp(S))
    float* Spart = P + (size_t)NB * NQL * ML;         // [16][4][512] partial row sums

    dim3 gProj(NQL / 32, HDIM / 64, NB * 2);
    proj_kernel<<<gProj, 256, 0, stream>>>(query, key, Wq, Wk, EqT, EkT);

    dim3 gSc(ML / 32, NQL / 32, NB);
    scores_kernel<<<gSc, 256, 0, stream>>>(EqT, EkT, Wv, P, Spart);

    dim3 gAv(DDIM / 64, NQL / 16, NB);
    av_kernel<<<gAv, 256, 0, stream>>>(P, Spart, value, out);
}

// Round 10
// 133.796 us; speedup vs baseline: 1.0728x; 1.0728x over previous
//
#include <hip/hip_runtime.h>
#include <hip/hip_bf16.h>

// Problem dims (AdditiveAttention_56865366999388)
#define NB 4
#define NQL 512   // query length
#define ML 512    // key/value length
#define DDIM 256  // DQ == DK == DV
#define HDIM 256  // H

static constexpr float TWO_LOG2E = 2.8853900817779268f; // 2*log2(e)
static constexpr float LOG2E     = 1.4426950408889634f;

// ---------------------------------------------------------------------------
// Kernel 1: projection + exp.  (byte-identical to the 133.6us r8 kernel)
// ---------------------------------------------------------------------------
__global__ __launch_bounds__(256) void proj_kernel(
    const float* __restrict__ q_src, const float* __restrict__ k_src,
    const float* __restrict__ Wq,    const float* __restrict__ Wk,
    float* __restrict__ EqT,         float* __restrict__ EkT)
{
    const int z = blockIdx.z;
    const int b = z & 3;
    const int which = z >> 2;
    const float* __restrict__ src  = which ? k_src : q_src;
    const float* __restrict__ W    = which ? Wk    : Wq;
    float* __restrict__       outT = which ? EkT   : EqT;

    const int l0 = blockIdx.x * 32;
    const int h0 = blockIdx.y * 64;
    const int t  = threadIdx.x;
    const int tx = t & 15;   // h group (4 each)
    const int ty = t >> 4;   // l (2 each)

    __shared__ float sX[32][36];   // [dd][ll]  32d x 32l
    __shared__ float sW[32][68];   // [dd][hh]  32d x 64h

    float acc[2][4];
    #pragma unroll
    for (int i = 0; i < 2; i++)
        #pragma unroll
        for (int j = 0; j < 4; j++) acc[i][j] = 0.f;

    const int llA = t >> 3, dgA = t & 7;   // X: 32 l rows x 8 d-groups(4)
    const int ddB = t >> 3, hgB = t & 7;   // W: 32 d rows x 8 h-groups(8)

    for (int d0 = 0; d0 < DDIM; d0 += 32) {
        float4 xv = *(const float4*)&src[(size_t)(b * NQL + l0 + llA) * DDIM + d0 + dgA * 4];
        const float* wrow = &W[(size_t)(d0 + ddB) * HDIM + h0 + hgB * 8];
        float4 wa = ((const float4*)wrow)[0];
        float4 wb = ((const float4*)wrow)[1];
        __syncthreads();
        sX[dgA * 4 + 0][llA] = xv.x;
        sX[dgA * 4 + 1][llA] = xv.y;
        sX[dgA * 4 + 2][llA] = xv.z;
        sX[dgA * 4 + 3][llA] = xv.w;
        *(float4*)&sW[ddB][hgB * 8]     = wa;
        *(float4*)&sW[ddB][hgB * 8 + 4] = wb;
        __syncthreads();
        #pragma unroll
        for (int dd = 0; dd < 32; dd++) {
            float4 w4 = *(const float4*)&sW[dd][tx * 4];
            float2 x2 = *(const float2*)&sX[dd][ty * 2];
            acc[0][0] = fmaf(x2.x, w4.x, acc[0][0]);
            acc[0][1] = fmaf(x2.x, w4.y, acc[0][1]);
            acc[0][2] = fmaf(x2.x, w4.z, acc[0][2]);
            acc[0][3] = fmaf(x2.x, w4.w, acc[0][3]);
            acc[1][0] = fmaf(x2.y, w4.x, acc[1][0]);
            acc[1][1] = fmaf(x2.y, w4.y, acc[1][1]);
            acc[1][2] = fmaf(x2.y, w4.z, acc[1][2]);
            acc[1][3] = fmaf(x2.y, w4.w, acc[1][3]);
        }
    }

    #pragma unroll
    for (int j = 0; j < 4; j++) {
        float2 o;
        o.x = __builtin_amdgcn_exp2f(acc[0][j] * TWO_LOG2E);
        o.y = __builtin_amdgcn_exp2f(acc[1][j] * TWO_LOG2E);
        *(float2*)&outT[(size_t)(b * HDIM + h0 + tx * 4 + j) * NQL + l0 + ty * 2] = o;
    }
}

// ---------------------------------------------------------------------------
// Kernel 2: scores + exp + partial row sums.  (THE ONE CHANGE this round)
// r9 counters: 42.5us, VALUBusy 57%, conflicts 0 -> LDS-issue-bound at
// 0.074 LDS-cy/eval (q b64 + k b64 + sWV b32 per 4 evals/thread).
// Fix: (1) Wv via uniform scalar load (s_load), sWV deleted;
//      (2) per-thread 2n x 4m -> k-read is one b128 covering 2x evals.
// New bill: q b64(7) + k b128(12) = 19 cy per 512 lane-evals = 0.037.
// Tile 32n x 64m, 256 thr, grid (8,16,4) = 512 blocks (2/CU).
// Math unchanged: tanh(q+k) = 1 - 2/(e^{2q}e^{2k}+1);
//   S = sum_h Wv[h] - 2*sum_h Wv[h]/a, a = fma(Eq,Ek,1); paired rcp;
//   P = exp(S) unnormalized (|S| <= ~13, fp32-safe).
// ---------------------------------------------------------------------------
__global__ __launch_bounds__(256) void scores_kernel(
    const float* __restrict__ EqT, const float* __restrict__ EkT,
    const float* __restrict__ Wv, float* __restrict__ P,
    float* __restrict__ Spart)
{
    const int b  = blockIdx.z;
    const int mt = blockIdx.x;
    const int m0 = mt * 64;
    const int n0 = blockIdx.y * 32;
    const int t  = threadIdx.x;
    const int tx = t & 15;   // m quad (4 each)
    const int ty = t >> 4;   // n pair (2 each)

    __shared__ float sQ[32][36];   // [hh][nn] 32h x 32n (+pad)
    __shared__ float sK[32][68];   // [hh][mm] 32h x 64m (+pad)

    float acc0[4] = {}, acc1[4] = {};
    float swv = 0.f;

    const int hhA = t >> 3, cgA = t & 7;  // q staging: 32 h rows x 8 grps(4)
    const int hhK = t >> 3, ckK = t & 7;  // k staging: 32 h rows x 8 grps(8)

    for (int h0 = 0; h0 < HDIM; h0 += 32) {
        float4 qv = *(const float4*)&EqT[(size_t)(b * HDIM + h0 + hhA) * NQL + n0 + cgA * 4];
        const float* krow = &EkT[(size_t)(b * HDIM + h0 + hhK) * ML + m0 + ckK * 8];
        float4 ka = ((const float4*)krow)[0];
        float4 kb = ((const float4*)krow)[1];
        __syncthreads();
        *(float4*)&sQ[hhA][cgA * 4]     = qv;
        *(float4*)&sK[hhK][ckK * 8]     = ka;
        *(float4*)&sK[hhK][ckK * 8 + 4] = kb;
        __syncthreads();
        #pragma unroll 8
        for (int hh = 0; hh < 32; hh++) {
            float2 q2 = *(const float2*)&sQ[hh][ty * 2];
            float4 k4 = *(const float4*)&sK[hh][tx * 4];
            const float wv = Wv[h0 + hh];      // block-uniform -> s_load
            swv += wv;
            const float nw2 = -2.0f * wv;
            {   // n-row 0
                float a0 = fmaf(q2.x, k4.x, 1.0f);   // e^{2(q+k)} + 1
                float a1 = fmaf(q2.x, k4.y, 1.0f);
                float a2 = fmaf(q2.x, k4.z, 1.0f);
                float a3 = fmaf(q2.x, k4.w, 1.0f);
                float r01 = __builtin_amdgcn_rcpf(a0 * a1);
                float r23 = __builtin_amdgcn_rcpf(a2 * a3);
                float t01 = nw2 * r01, t23 = nw2 * r23;
                acc0[0] = fmaf(t01, a1, acc0[0]);
                acc0[1] = fmaf(t01, a0, acc0[1]);
                acc0[2] = fmaf(t23, a3, acc0[2]);
                acc0[3] = fmaf(t23, a2, acc0[3]);
            }
            {   // n-row 1
                float a0 = fmaf(q2.y, k4.x, 1.0f);
                float a1 = fmaf(q2.y, k4.y, 1.0f);
                float a2 = fmaf(q2.y, k4.z, 1.0f);
                float a3 = fmaf(q2.y, k4.w, 1.0f);
                float r01 = __builtin_amdgcn_rcpf(a0 * a1);
                float r23 = __builtin_amdgcn_rcpf(a2 * a3);
                float t01 = nw2 * r01, t23 = nw2 * r23;
                acc1[0] = fmaf(t01, a1, acc1[0]);
                acc1[1] = fmaf(t01, a0, acc1[1]);
                acc1[2] = fmaf(t23, a3, acc1[2]);
                acc1[3] = fmaf(t23, a2, acc1[3]);
            }
        }
    }

    // epilogue: P = exp(S) + per-block partial rowsums (over this block's 64 m)
    float rs0, rs1;
    {
        float4 p;
        p.x = __builtin_amdgcn_exp2f((swv + acc0[0]) * LOG2E);
        p.y = __builtin_amdgcn_exp2f((swv + acc0[1]) * LOG2E);
        p.z = __builtin_amdgcn_exp2f((swv + acc0[2]) * LOG2E);
        p.w = __builtin_amdgcn_exp2f((swv + acc0[3]) * LOG2E);
        *(float4*)&P[(size_t)(b * NQL + n0 + ty * 2 + 0) * ML + m0 + tx * 4] = p;
        rs0 = (p.x + p.y) + (p.z + p.w);
    }
    {
        float4 p;
        p.x = __builtin_amdgcn_exp2f((swv + acc1[0]) * LOG2E);
        p.y = __builtin_amdgcn_exp2f((swv + acc1[1]) * LOG2E);
        p.z = __builtin_amdgcn_exp2f((swv + acc1[2]) * LOG2E);
        p.w = __builtin_amdgcn_exp2f((swv + acc1[3]) * LOG2E);
        *(float4*)&P[(size_t)(b * NQL + n0 + ty * 2 + 1) * ML + m0 + tx * 4] = p;
        rs1 = (p.x + p.y) + (p.z + p.w);
    }
    #pragma unroll
    for (int off = 1; off < 16; off <<= 1) {   // reduce across the 16 tx lanes
        rs0 += __shfl_xor(rs0, off);
        rs1 += __shfl_xor(rs1, off);
    }
    if (tx == 0) {
        Spart[(size_t)(mt * NB + b) * NQL + n0 + ty * 2 + 0] = rs0;
        Spart[(size_t)(mt * NB + b) * NQL + n0 + ty * 2 + 1] = rs1;
    }
}

// ---------------------------------------------------------------------------
// Kernel 3: out[b][n][v] = (sum_m P * V) / rowsum.  (r8-av restored; only
// diff: 8 Spart partials now, matching the 64-wide scores m-tiles)
// grid: (4, 32, 4) = 512 blocks. block 256. 16n x 64v tile, 1n x 4v/thread.
// ---------------------------------------------------------------------------
__global__ __launch_bounds__(256) void av_kernel(
    const float* __restrict__ A, const float* __restrict__ Spart,
    const float* __restrict__ V, float* __restrict__ O)
{
    const int b  = blockIdx.z;
    const int v0 = blockIdx.x * 64;
    const int n0 = blockIdx.y * 16;
    const int t  = threadIdx.x;
    const int tx = t & 15;   // v group (4 each)
    const int ty = t >> 4;   // n (1 each)

    __shared__ float sA[32][20];  // [mm][nn] 32m x 16n
    __shared__ float sV[32][68];  // [mm][vv] 32m x 64v
    __shared__ float sInv[16];

    if (t < 16) {   // softmax denominators from the 8 scores partials
        float s = 0.f;
        #pragma unroll
        for (int mt = 0; mt < 8; ++mt)
            s += Spart[(size_t)(mt * NB + b) * NQL + n0 + t];
        sInv[t] = 1.0f / s;
    }

    float4 acc = {0.f, 0.f, 0.f, 0.f};

    const int nnA = t >> 4, mgA = t & 15;  // A: 16 n rows x 16 m-groups(2)
    const int mmB = t >> 3, vgB = t & 7;   // V: 32 m rows x 8 v-groups(8)

    for (int m0 = 0; m0 < ML; m0 += 32) {
        float2 av = *(const float2*)&A[(size_t)(b * NQL + n0 + nnA) * ML + m0 + mgA * 2];
        const float* vrow = &V[(size_t)(b * ML + m0 + mmB) * DDIM + v0 + vgB * 8];
        float4 va = ((const float4*)vrow)[0];
        float4 vb = ((const float4*)vrow)[1];
        __syncthreads();
        sA[mgA * 2 + 0][nnA] = av.x;
        sA[mgA * 2 + 1][nnA] = av.y;
        *(float4*)&sV[mmB][vgB * 8]     = va;
        *(float4*)&sV[mmB][vgB * 8 + 4] = vb;
        __syncthreads();
        #pragma unroll
        for (int mm = 0; mm < 32; mm++) {
            float a = sA[mm][ty];
            float4 v4 = *(const float4*)&sV[mm][tx * 4];
            acc.x = fmaf(a, v4.x, acc.x);
            acc.y = fmaf(a, v4.y, acc.y);
            acc.z = fmaf(a, v4.z, acc.z);
            acc.w = fmaf(a, v4.w, acc.w);
        }
    }

    const float inv = sInv[ty];
    float4 o;
    o.x = acc.x * inv;
    o.y = acc.y * inv;
    o.z = acc.z * inv;
    o.w = acc.w * inv;
    *(float4*)&O[(size_t)(b * NQL + n0 + ty) * DDIM + v0 + tx * 4] = o;
}

// ---------------------------------------------------------------------------
extern "C" void kernel_launch(void* const* d_in, const int* in_sizes, int n_in,
                              void* d_out, int out_size, void* d_ws, size_t ws_size,
                              hipStream_t stream)
{
    const float* query = (const float*)d_in[0]; // (4,512,256)
    const float* key   = (const float*)d_in[1]; // (4,512,256)
    const float* value = (const float*)d_in[2]; // (4,512,256)
    const float* Wq    = (const float*)d_in[3]; // (256,256)
    const float* Wk    = (const float*)d_in[4]; // (256,256)
    const float* Wv    = (const float*)d_in[5]; // (256,)
    float* out = (float*)d_out;                 // (4,512,256)

    // workspace layout (fp32): EqT 2MB | EkT 2MB | P 4MB | Spart 64KB
    float* EqT   = (float*)d_ws;                      // [4][256][512]
    float* EkT   = EqT + (size_t)NB * HDIM * NQL;     // [4][256][512]
    float* P     = EkT + (size_t)NB * HDIM * ML;      // [4][512][512] (= exp(S))
    float* Spart = P + (size_t)NB * NQL * ML;         // [8][4][512] partial row sums

    dim3 gProj(NQL / 32, HDIM / 64, NB * 2);
    proj_kernel<<<gProj, 256, 0, stream>>>(query, key, Wq, Wk, EqT, EkT);

    dim3 gSc(ML / 64, NQL / 32, NB);
    scores_kernel<<<gSc, 256, 0, stream>>>(EqT, EkT, Wv, P, Spart);

    dim3 gAv(DDIM / 64, NQL / 16, NB);
    av_kernel<<<gAv, 256, 0, stream>>>(P, Spart, value, out);
}

// Round 11
// 131.777 us; speedup vs baseline: 1.0892x; 1.0153x over previous
//
#include <hip/hip_runtime.h>
#include <hip/hip_bf16.h>

// Problem dims (AdditiveAttention_56865366999388)
#define NB 4
#define NQL 512   // query length
#define ML 512    // key/value length
#define DDIM 256  // DQ == DK == DV
#define HDIM 256  // H

static constexpr float TWO_LOG2E = 2.8853900817779268f; // 2*log2(e)
static constexpr float LOG2E     = 1.4426950408889634f;

// ---------------------------------------------------------------------------
// Kernel 1: projection + exp.  (byte-identical to r10)
// ---------------------------------------------------------------------------
__global__ __launch_bounds__(256) void proj_kernel(
    const float* __restrict__ q_src, const float* __restrict__ k_src,
    const float* __restrict__ Wq,    const float* __restrict__ Wk,
    float* __restrict__ EqT,         float* __restrict__ EkT)
{
    const int z = blockIdx.z;
    const int b = z & 3;
    const int which = z >> 2;
    const float* __restrict__ src  = which ? k_src : q_src;
    const float* __restrict__ W    = which ? Wk    : Wq;
    float* __restrict__       outT = which ? EkT   : EqT;

    const int l0 = blockIdx.x * 32;
    const int h0 = blockIdx.y * 64;
    const int t  = threadIdx.x;
    const int tx = t & 15;   // h group (4 each)
    const int ty = t >> 4;   // l (2 each)

    __shared__ float sX[32][36];   // [dd][ll]  32d x 32l
    __shared__ float sW[32][68];   // [dd][hh]  32d x 64h

    float acc[2][4];
    #pragma unroll
    for (int i = 0; i < 2; i++)
        #pragma unroll
        for (int j = 0; j < 4; j++) acc[i][j] = 0.f;

    const int llA = t >> 3, dgA = t & 7;   // X: 32 l rows x 8 d-groups(4)
    const int ddB = t >> 3, hgB = t & 7;   // W: 32 d rows x 8 h-groups(8)

    for (int d0 = 0; d0 < DDIM; d0 += 32) {
        float4 xv = *(const float4*)&src[(size_t)(b * NQL + l0 + llA) * DDIM + d0 + dgA * 4];
        const float* wrow = &W[(size_t)(d0 + ddB) * HDIM + h0 + hgB * 8];
        float4 wa = ((const float4*)wrow)[0];
        float4 wb = ((const float4*)wrow)[1];
        __syncthreads();
        sX[dgA * 4 + 0][llA] = xv.x;
        sX[dgA * 4 + 1][llA] = xv.y;
        sX[dgA * 4 + 2][llA] = xv.z;
        sX[dgA * 4 + 3][llA] = xv.w;
        *(float4*)&sW[ddB][hgB * 8]     = wa;
        *(float4*)&sW[ddB][hgB * 8 + 4] = wb;
        __syncthreads();
        #pragma unroll
        for (int dd = 0; dd < 32; dd++) {
            float4 w4 = *(const float4*)&sW[dd][tx * 4];
            float2 x2 = *(const float2*)&sX[dd][ty * 2];
            acc[0][0] = fmaf(x2.x, w4.x, acc[0][0]);
            acc[0][1] = fmaf(x2.x, w4.y, acc[0][1]);
            acc[0][2] = fmaf(x2.x, w4.z, acc[0][2]);
            acc[0][3] = fmaf(x2.x, w4.w, acc[0][3]);
            acc[1][0] = fmaf(x2.y, w4.x, acc[1][0]);
            acc[1][1] = fmaf(x2.y, w4.y, acc[1][1]);
            acc[1][2] = fmaf(x2.y, w4.z, acc[1][2]);
            acc[1][3] = fmaf(x2.y, w4.w, acc[1][3]);
        }
    }

    #pragma unroll
    for (int j = 0; j < 4; j++) {
        float2 o;
        o.x = __builtin_amdgcn_exp2f(acc[0][j] * TWO_LOG2E);
        o.y = __builtin_amdgcn_exp2f(acc[1][j] * TWO_LOG2E);
        *(float2*)&outT[(size_t)(b * HDIM + h0 + tx * 4 + j) * NQL + l0 + ty * 2] = o;
    }
}

// ---------------------------------------------------------------------------
// Kernel 2: scores + exp + partial row sums.  (byte-identical to r10)
// ---------------------------------------------------------------------------
__global__ __launch_bounds__(256) void scores_kernel(
    const float* __restrict__ EqT, const float* __restrict__ EkT,
    const float* __restrict__ Wv, float* __restrict__ P,
    float* __restrict__ Spart)
{
    const int b  = blockIdx.z;
    const int mt = blockIdx.x;
    const int m0 = mt * 64;
    const int n0 = blockIdx.y * 32;
    const int t  = threadIdx.x;
    const int tx = t & 15;   // m quad (4 each)
    const int ty = t >> 4;   // n pair (2 each)

    __shared__ float sQ[32][36];   // [hh][nn] 32h x 32n (+pad)
    __shared__ float sK[32][68];   // [hh][mm] 32h x 64m (+pad)

    float acc0[4] = {}, acc1[4] = {};
    float swv = 0.f;

    const int hhA = t >> 3, cgA = t & 7;  // q staging: 32 h rows x 8 grps(4)
    const int hhK = t >> 3, ckK = t & 7;  // k staging: 32 h rows x 8 grps(8)

    for (int h0 = 0; h0 < HDIM; h0 += 32) {
        float4 qv = *(const float4*)&EqT[(size_t)(b * HDIM + h0 + hhA) * NQL + n0 + cgA * 4];
        const float* krow = &EkT[(size_t)(b * HDIM + h0 + hhK) * ML + m0 + ckK * 8];
        float4 ka = ((const float4*)krow)[0];
        float4 kb = ((const float4*)krow)[1];
        __syncthreads();
        *(float4*)&sQ[hhA][cgA * 4]     = qv;
        *(float4*)&sK[hhK][ckK * 8]     = ka;
        *(float4*)&sK[hhK][ckK * 8 + 4] = kb;
        __syncthreads();
        #pragma unroll 8
        for (int hh = 0; hh < 32; hh++) {
            float2 q2 = *(const float2*)&sQ[hh][ty * 2];
            float4 k4 = *(const float4*)&sK[hh][tx * 4];
            const float wv = Wv[h0 + hh];      // block-uniform -> s_load
            swv += wv;
            const float nw2 = -2.0f * wv;
            {   // n-row 0
                float a0 = fmaf(q2.x, k4.x, 1.0f);   // e^{2(q+k)} + 1
                float a1 = fmaf(q2.x, k4.y, 1.0f);
                float a2 = fmaf(q2.x, k4.z, 1.0f);
                float a3 = fmaf(q2.x, k4.w, 1.0f);
                float r01 = __builtin_amdgcn_rcpf(a0 * a1);
                float r23 = __builtin_amdgcn_rcpf(a2 * a3);
                float t01 = nw2 * r01, t23 = nw2 * r23;
                acc0[0] = fmaf(t01, a1, acc0[0]);
                acc0[1] = fmaf(t01, a0, acc0[1]);
                acc0[2] = fmaf(t23, a3, acc0[2]);
                acc0[3] = fmaf(t23, a2, acc0[3]);
            }
            {   // n-row 1
                float a0 = fmaf(q2.y, k4.x, 1.0f);
                float a1 = fmaf(q2.y, k4.y, 1.0f);
                float a2 = fmaf(q2.y, k4.z, 1.0f);
                float a3 = fmaf(q2.y, k4.w, 1.0f);
                float r01 = __builtin_amdgcn_rcpf(a0 * a1);
                float r23 = __builtin_amdgcn_rcpf(a2 * a3);
                float t01 = nw2 * r01, t23 = nw2 * r23;
                acc1[0] = fmaf(t01, a1, acc1[0]);
                acc1[1] = fmaf(t01, a0, acc1[1]);
                acc1[2] = fmaf(t23, a3, acc1[2]);
                acc1[3] = fmaf(t23, a2, acc1[3]);
            }
        }
    }

    // epilogue: P = exp(S) + per-block partial rowsums (over this block's 64 m)
    float rs0, rs1;
    {
        float4 p;
        p.x = __builtin_amdgcn_exp2f((swv + acc0[0]) * LOG2E);
        p.y = __builtin_amdgcn_exp2f((swv + acc0[1]) * LOG2E);
        p.z = __builtin_amdgcn_exp2f((swv + acc0[2]) * LOG2E);
        p.w = __builtin_amdgcn_exp2f((swv + acc0[3]) * LOG2E);
        *(float4*)&P[(size_t)(b * NQL + n0 + ty * 2 + 0) * ML + m0 + tx * 4] = p;
        rs0 = (p.x + p.y) + (p.z + p.w);
    }
    {
        float4 p;
        p.x = __builtin_amdgcn_exp2f((swv + acc1[0]) * LOG2E);
        p.y = __builtin_amdgcn_exp2f((swv + acc1[1]) * LOG2E);
        p.z = __builtin_amdgcn_exp2f((swv + acc1[2]) * LOG2E);
        p.w = __builtin_amdgcn_exp2f((swv + acc1[3]) * LOG2E);
        *(float4*)&P[(size_t)(b * NQL + n0 + ty * 2 + 1) * ML + m0 + tx * 4] = p;
        rs1 = (p.x + p.y) + (p.z + p.w);
    }
    #pragma unroll
    for (int off = 1; off < 16; off <<= 1) {   // reduce across the 16 tx lanes
        rs0 += __shfl_xor(rs0, off);
        rs1 += __shfl_xor(rs1, off);
    }
    if (tx == 0) {
        Spart[(size_t)(mt * NB + b) * NQL + n0 + ty * 2 + 0] = rs0;
        Spart[(size_t)(mt * NB + b) * NQL + n0 + ty * 2 + 1] = rs1;
    }
}

// ---------------------------------------------------------------------------
// Kernel 3 (THE ONE CHANGE): out[b][n][v] = (sum_m P * V) / rowsum.
// A is read DIRECTLY from global in the inner loop (sA + its staging
// deleted): per 4 mm one float4 load, 4 distinct 16B addrs/wave
// (broadcast-coalesced), L2-hot (P written by scores just before).
// LDS bill drops 17 -> 12 cy per wave-mm (v b128 only): model 29 -> 20.5us.
// V staging keeps the proven reg-prefetch + 2-barrier structure.
// grid: (4, 32, 4) = 512 blocks. block 256. 16n x 64v tile, 1n x 4v/thread.
// ---------------------------------------------------------------------------
__global__ __launch_bounds__(256) void av_kernel(
    const float* __restrict__ P, const float* __restrict__ Spart,
    const float* __restrict__ V, float* __restrict__ O)
{
    const int b  = blockIdx.z;
    const int v0 = blockIdx.x * 64;
    const int n0 = blockIdx.y * 16;
    const int t  = threadIdx.x;
    const int tx = t & 15;   // v group (4 each)
    const int ty = t >> 4;   // n (1 each)

    __shared__ float sV[32][68];  // [mm][vv] 32m x 64v
    __shared__ float sInv[16];

    if (t < 16) {   // softmax denominators from the 8 scores partials
        float s = 0.f;
        #pragma unroll
        for (int mt = 0; mt < 8; ++mt)
            s += Spart[(size_t)(mt * NB + b) * NQL + n0 + t];
        sInv[t] = 1.0f / s;
    }

    float4 acc = {0.f, 0.f, 0.f, 0.f};

    const int mmB = t >> 3, vgB = t & 7;   // V: 32 m rows x 8 v-groups(8)
    const float* prow = &P[(size_t)(b * NQL + n0 + ty) * ML];  // this thread's n-row

    // reg-prefetch V chunk 0
    const float* vrow0 = &V[(size_t)(b * ML + mmB) * DDIM + v0 + vgB * 8];
    float4 va = ((const float4*)vrow0)[0];
    float4 vb = ((const float4*)vrow0)[1];

    for (int m0 = 0; m0 < ML; m0 += 32) {
        __syncthreads();
        *(float4*)&sV[mmB][vgB * 8]     = va;
        *(float4*)&sV[mmB][vgB * 8 + 4] = vb;
        __syncthreads();
        if (m0 + 32 < ML) {   // prefetch next V chunk; hides under compute
            const float* vrow = &V[(size_t)(b * ML + m0 + 32 + mmB) * DDIM + v0 + vgB * 8];
            va = ((const float4*)vrow)[0];
            vb = ((const float4*)vrow)[1];
        }
        #pragma unroll
        for (int mg = 0; mg < 8; ++mg) {
            float4 a4 = *(const float4*)&prow[m0 + mg * 4];   // global, broadcast
            float4 w0 = *(const float4*)&sV[mg * 4 + 0][tx * 4];
            float4 w1 = *(const float4*)&sV[mg * 4 + 1][tx * 4];
            float4 w2 = *(const float4*)&sV[mg * 4 + 2][tx * 4];
            float4 w3 = *(const float4*)&sV[mg * 4 + 3][tx * 4];
            acc.x = fmaf(a4.x, w0.x, acc.x);
            acc.y = fmaf(a4.x, w0.y, acc.y);
            acc.z = fmaf(a4.x, w0.z, acc.z);
            acc.w = fmaf(a4.x, w0.w, acc.w);
            acc.x = fmaf(a4.y, w1.x, acc.x);
            acc.y = fmaf(a4.y, w1.y, acc.y);
            acc.z = fmaf(a4.y, w1.z, acc.z);
            acc.w = fmaf(a4.y, w1.w, acc.w);
            acc.x = fmaf(a4.z, w2.x, acc.x);
            acc.y = fmaf(a4.z, w2.y, acc.y);
            acc.z = fmaf(a4.z, w2.z, acc.z);
            acc.w = fmaf(a4.z, w2.w, acc.w);
            acc.x = fmaf(a4.w, w3.x, acc.x);
            acc.y = fmaf(a4.w, w3.y, acc.y);
            acc.z = fmaf(a4.w, w3.z, acc.z);
            acc.w = fmaf(a4.w, w3.w, acc.w);
        }
    }

    const float inv = sInv[ty];
    float4 o;
    o.x = acc.x * inv;
    o.y = acc.y * inv;
    o.z = acc.z * inv;
    o.w = acc.w * inv;
    *(float4*)&O[(size_t)(b * NQL + n0 + ty) * DDIM + v0 + tx * 4] = o;
}

// ---------------------------------------------------------------------------
extern "C" void kernel_launch(void* const* d_in, const int* in_sizes, int n_in,
                              void* d_out, int out_size, void* d_ws, size_t ws_size,
                              hipStream_t stream)
{
    const float* query = (const float*)d_in[0]; // (4,512,256)
    const float* key   = (const float*)d_in[1]; // (4,512,256)
    const float* value = (const float*)d_in[2]; // (4,512,256)
    const float* Wq    = (const float*)d_in[3]; // (256,256)
    const float* Wk    = (const float*)d_in[4]; // (256,256)
    const float* Wv    = (const float*)d_in[5]; // (256,)
    float* out = (float*)d_out;                 // (4,512,256)

    // workspace layout (fp32): EqT 2MB | EkT 2MB | P 4MB | Spart 64KB
    float* EqT   = (float*)d_ws;                      // [4][256][512]
    float* EkT   = EqT + (size_t)NB * HDIM * NQL;     // [4][256][512]
    float* P     = EkT + (size_t)NB * HDIM * ML;      // [4][512][512] (= exp(S))
    float* Spart = P + (size_t)NB * NQL * ML;         // [8][4][512] partial row sums

    dim3 gProj(NQL / 32, HDIM / 64, NB * 2);
    proj_kernel<<<gProj, 256, 0, stream>>>(query, key, Wq, Wk, EqT, EkT);

    dim3 gSc(ML / 64, NQL / 32, NB);
    scores_kernel<<<gSc, 256, 0, stream>>>(EqT, EkT, Wv, P, Spart);

    dim3 gAv(DDIM / 64, NQL / 16, NB);
    av_kernel<<<gAv, 256, 0, stream>>>(P, Spart, value, out);
}